// Round 6
// baseline (178.154 us; speedup 1.0000x reference)
//
#include <hip/hip_runtime.h>
#include <math.h>

// Problem constants (B, N, C, T, H, G) = (8, 256, 128, 64, 4, 12), D = 32
namespace {
constexpr int kB = 8, kN = 256, kC = 128, kT = 64, kH = 4, kG = 12, kD = 32;
constexpr float kEps = 1e-6f;
constexpr float kInvSqrtC = 0.08838834764831845f;   // 1/sqrt(128)
constexpr float kInvSqrtD = 0.17677669529663687f;   // 1/sqrt(32)

// workspace layout (float offsets)
constexpr int WS_Q     = 0;                          // [b][n][c]  (pre-scaled by 1/sqrt(D))
constexpr int WS_KT    = WS_Q + kB*kN*kC;            // [b][c][n]  TRANSPOSED K
constexpr int WS_V     = WS_KT + kB*kN*kC;           // [b][n][c]
constexpr int WS_SIZES = WS_V + kB*kN*kC;            // [b][n][3]
constexpr int WS_KTXT  = WS_SIZES + kB*kN*3;         // [b][t][c]
constexpr int WS_VTXT  = WS_KTXT + kB*kT*kC;         // [b][t][c]
constexpr int WS_WKF   = WS_VTXT + kB*kT*kC;         // [b][g][t] = (Wrel @ k_txt^T)/sqrt(C)
constexpr int WS_SK    = WS_WKF + kB*kG*kT;          // [b][t]    = (brel . k_txt[t])/sqrt(C)
constexpr int WS_VB    = WS_SK + kB*kT;              // [b][t][h] = v_txt @ Wbias
constexpr int WS_WB1   = WS_VB + kB*kT*kH;           // [g][h]    = Wrel @ Wbias
constexpr int WS_CB    = WS_WB1 + kG*kH;             // [h]       = brel@Wbias + bbias
constexpr int WS_BIAS  = WS_CB + kH;                 // [b][i][j][h]  (8 MB)

// proj grid: 4 rows per block, 256 threads (each thread: 2 rows x 1 col)
constexpr int kProjQKV  = (kB*kN)/4;     // 512 blocks
constexpr int kProjTxt  = (kB*kT)/4;     // 128 blocks
constexpr int kProjSize = (kB*kN)/256;   // 8 blocks (sizes from corners)

// fold tasks: per batch 768 (WkF) + 64 (sk) + 256 (VB) = 1088; global 48+4
constexpr int kTasksPerB = kG*kT + kT + kT*kH;       // 1088
constexpr int kTasksAll  = kB*kTasksPerB;            // 8704
constexpr int kTasksTot  = kTasksAll + kG*kH + kH;   // 8756
constexpr int kFoldBlocks = (kTasksTot + 3) / 4;     // 4 waves / block

constexpr int TI = 4;                    // i-rows per attn block
}

// ---------------------------------------------------------------------------
// Kernel 1: fused linear projections.
//   blocks [0,512)    : q/k/v, 4 feat rows per block (thread = 2 rows x 1 col)
//   blocks [512,640)  : k_txt/v_txt, 4 lang rows per block
//   blocks [640,648)  : box sizes from corners (256 boxes per block)
// ---------------------------------------------------------------------------
static __global__ __launch_bounds__(256)
void proj_kernel(const float* __restrict__ feat, const float* __restrict__ lang,
                 const float* __restrict__ corners,
                 const float* __restrict__ Wq, const float* __restrict__ bq,
                 const float* __restrict__ Wk, const float* __restrict__ bk,
                 const float* __restrict__ Wv, const float* __restrict__ bv,
                 const float* __restrict__ Wtk, const float* __restrict__ btk,
                 const float* __restrict__ Wtv, const float* __restrict__ btv,
                 float* __restrict__ ws)
{
  const int blk = blockIdx.x;
  const int tid = threadIdx.x;
  __shared__ float rows[4][kC];

  if (blk < kProjQKV) {
    const int r0 = blk * 4;                       // global row (b*N + n)
    rows[tid >> 7][tid & 127] = feat[(size_t)r0*kC + tid];
    rows[(tid + 256) >> 7][tid & 127] = feat[(size_t)r0*kC + tid + 256];
    __syncthreads();

    const int c = tid & 127;
    const int p = tid >> 7;                       // row-pair select
    const int ra = p*2, rb = p*2 + 1;

    float aq0 = bq[c], aq1 = aq0;
    float ak0 = bk[c], ak1 = ak0;
    float av0 = bv[c], av1 = av0;
#pragma unroll 4
    for (int d = 0; d < kC; ++d) {
      const float wq = Wq[d*kC + c], wk = Wk[d*kC + c], wv = Wv[d*kC + c];
      const float fa = rows[ra][d], fb = rows[rb][d];
      aq0 = fmaf(fa, wq, aq0); aq1 = fmaf(fb, wq, aq1);
      ak0 = fmaf(fa, wk, ak0); ak1 = fmaf(fb, wk, ak1);
      av0 = fmaf(fa, wv, av0); av1 = fmaf(fb, wv, av1);
    }

    const int gra = r0 + ra, grb = r0 + rb;
    const int bb = r0 / kN, n0 = r0 % kN;
    ws[WS_Q + (size_t)gra*kC + c] = aq0 * kInvSqrtD;   // fold 1/sqrt(D)
    ws[WS_Q + (size_t)grb*kC + c] = aq1 * kInvSqrtD;
    ws[WS_KT + (size_t)bb*kC*kN + c*kN + n0 + ra] = ak0;   // transposed K
    ws[WS_KT + (size_t)bb*kC*kN + c*kN + n0 + rb] = ak1;
    ws[WS_V + (size_t)gra*kC + c] = av0;
    ws[WS_V + (size_t)grb*kC + c] = av1;
  } else if (blk < kProjQKV + kProjTxt) {
    const int r0 = (blk - kProjQKV) * 4;          // 0 .. B*T-1
    rows[tid >> 7][tid & 127] = lang[(size_t)r0*kC + tid];
    rows[(tid + 256) >> 7][tid & 127] = lang[(size_t)r0*kC + tid + 256];
    __syncthreads();

    const int c = tid & 127;
    const int p = tid >> 7;
    const int ra = p*2, rb = p*2 + 1;

    float ak0 = btk[c], ak1 = ak0;
    float av0 = btv[c], av1 = av0;
#pragma unroll 4
    for (int d = 0; d < kC; ++d) {
      const float wk = Wtk[d*kC + c], wv = Wtv[d*kC + c];
      const float fa = rows[ra][d], fb = rows[rb][d];
      ak0 = fmaf(fa, wk, ak0); ak1 = fmaf(fb, wk, ak1);
      av0 = fmaf(fa, wv, av0); av1 = fmaf(fb, wv, av1);
    }
    ws[WS_KTXT + (size_t)(r0 + ra)*kC + c] = ak0;
    ws[WS_KTXT + (size_t)(r0 + rb)*kC + c] = ak1;
    ws[WS_VTXT + (size_t)(r0 + ra)*kC + c] = av0;
    ws[WS_VTXT + (size_t)(r0 + rb)*kC + c] = av1;
  } else {
    const int n = (blk - kProjQKV - kProjTxt) * 256 + tid;  // 0 .. B*N-1
    const float* cp = corners + (size_t)n * 24;
    float mn0 = cp[0], mn1 = cp[1], mn2 = cp[2];
    float mx0 = mn0, mx1 = mn1, mx2 = mn2;
#pragma unroll
    for (int k = 1; k < 8; ++k) {
      const float v0 = cp[k*3+0], v1 = cp[k*3+1], v2 = cp[k*3+2];
      mn0 = fminf(mn0, v0); mx0 = fmaxf(mx0, v0);
      mn1 = fminf(mn1, v1); mx1 = fmaxf(mx1, v1);
      mn2 = fminf(mn2, v2); mx2 = fmaxf(mx2, v2);
    }
    ws[WS_SIZES + n*3 + 0] = mx0 - mn0;
    ws[WS_SIZES + n*3 + 1] = mx1 - mn1;
    ws[WS_SIZES + n*3 + 2] = mx2 - mn2;
  }
}

// ---------------------------------------------------------------------------
// Kernel 2: algebraic folds — one WAVE per 128-length dot product.
// WkF and sk outputs are pre-scaled by 1/sqrt(C).
// ---------------------------------------------------------------------------
static __global__ __launch_bounds__(256)
void fold_kernel(const float* __restrict__ Wrel, const float* __restrict__ brel,
                 const float* __restrict__ Wbias, const float* __restrict__ bbias,
                 float* __restrict__ ws)
{
  const int task = blockIdx.x * 4 + (threadIdx.x >> 6);
  const int lane = threadIdx.x & 63;
  if (task >= kTasksTot) return;

  const float* x; const float* y; float* outp; float addend = 0.f;
  float mul = 1.f;
  int ystride4 = 0;   // if nonzero, y is a column of Wbias (stride kH)

  if (task < kTasksAll) {
    const int b = task / kTasksPerB;
    const int tt = task % kTasksPerB;
    const float* ktxt = ws + WS_KTXT + (size_t)b*kT*kC;
    const float* vtxt = ws + WS_VTXT + (size_t)b*kT*kC;
    if (tt < kG*kT) {
      const int g = tt >> 6, t = tt & 63;
      x = Wrel + g*kC; y = ktxt + t*kC; mul = kInvSqrtC;
      outp = ws + WS_WKF + b*kG*kT + g*kT + t;
    } else if (tt < kG*kT + kT) {
      const int t = tt - kG*kT;
      x = brel; y = ktxt + t*kC; mul = kInvSqrtC;
      outp = ws + WS_SK + b*kT + t;
    } else {
      const int idx = tt - kG*kT - kT;
      const int t = idx >> 2, h = idx & 3;
      x = vtxt + t*kC; y = Wbias + h; ystride4 = 1;
      outp = ws + WS_VB + b*kT*kH + t*kH + h;
    }
  } else {
    const int tt = task - kTasksAll;
    if (tt < kG*kH) {
      const int g = tt >> 2, h = tt & 3;
      x = Wrel + g*kC; y = Wbias + h; ystride4 = 1;
      outp = ws + WS_WB1 + g*kH + h;
    } else {
      const int h = tt - kG*kH;
      x = brel; y = Wbias + h; ystride4 = 1;
      addend = bbias[h];
      outp = ws + WS_CB + h;
    }
  }

  float p;
  if (ystride4) {
    p = x[lane]*y[lane*kH] + x[lane+64]*y[(lane+64)*kH];
  } else {
    p = x[lane]*y[lane] + x[lane+64]*y[lane+64];
  }
#pragma unroll
  for (int off = 32; off >= 1; off >>= 1) p += __shfl_xor(p, off, 64);
  if (lane == 0) *outp = p * mul + addend;
}

// ---------------------------------------------------------------------------
// Kernel 3a: bias kernel. One block per (b, i); thread j in [0,256).
//   geom -> folded scores (float4-vectorized uniform loads, online softmax)
//   -> bias[4] -> ws.
// ---------------------------------------------------------------------------
static __global__ __launch_bounds__(256, 4)
void bias_kernel(const float* __restrict__ centers,
                 const float* __restrict__ ws_ro, float* __restrict__ ws)
{
  const int i = blockIdx.x;
  const int b = blockIdx.y;
  const int j = threadIdx.x;

  // uniform (scalar) i-operands
  const float* cI = centers + (size_t)(b*kN + i)*3;
  const float* sI = ws_ro + WS_SIZES + (size_t)(b*kN + i)*3;
  const float cix = cI[0], ciy = cI[1], ciz = cI[2];
  const float six = sI[0], siy = sI[1], siz = sI[2];

  // per-thread j-operands
  const float* cJ = centers + (size_t)(b*kN + j)*3;
  const float* sJ = ws_ro + WS_SIZES + (size_t)(b*kN + j)*3;

  float g[kG];
  {
    const float dx = cJ[0] - cix;
    const float dy = cJ[1] - ciy;
    const float dz = cJ[2] - ciz;
    const float dist = sqrtf(dx*dx + dy*dy + dz*dz);
    const float horiz = sqrtf(dx*dx + dy*dy);
    g[0] = dx; g[1] = dy; g[2] = dz;
    g[3] = __logf(dist + kEps);
    g[4] = horiz;
    g[5] = dz / (dist + kEps);
    const float sjx = sJ[0], sjy = sJ[1], sjz = sJ[2];
    g[6] = sjx - six; g[7] = sjy - siy; g[8] = sjz - siz;
    g[9]  = sjx / (six + kEps);
    g[10] = sjy / (siy + kEps);
    g[11] = sjz / (siz + kEps);
  }

  // float4 views of the uniform per-batch tables (all 16B-aligned)
  const float4* __restrict__ wkf4 = (const float4*)(ws_ro + WS_WKF + b*kG*kT); // [g][t/4]
  const float4* __restrict__ sk4  = (const float4*)(ws_ro + WS_SK  + b*kT);    // [t/4]
  const float4* __restrict__ vb4  = (const float4*)(ws_ro + WS_VB  + b*kT*kH); // [t] (h in lanes)
  const float* __restrict__ wb1 = ws_ro + WS_WB1;
  const float* __restrict__ cbv = ws_ro + WS_CB;

  float m = -1e30f, ssum = 0.f;
  float a0 = 0.f, a1 = 0.f, a2 = 0.f, a3 = 0.f;
#pragma unroll
  for (int ch = 0; ch < 2; ++ch) {            // two chunks of 32 t's
    float4 sc4[8];
#pragma unroll
    for (int t4 = 0; t4 < 8; ++t4) sc4[t4] = sk4[ch*8 + t4];
#pragma unroll
    for (int gg = 0; gg < kG; ++gg) {
      const float gv = g[gg];
#pragma unroll
      for (int t4 = 0; t4 < 8; ++t4) {
        const float4 wv = wkf4[gg*(kT/4) + ch*8 + t4];
        sc4[t4].x = fmaf(gv, wv.x, sc4[t4].x);
        sc4[t4].y = fmaf(gv, wv.y, sc4[t4].y);
        sc4[t4].z = fmaf(gv, wv.z, sc4[t4].z);
        sc4[t4].w = fmaf(gv, wv.w, sc4[t4].w);
      }
    }
    float cm = -1e30f;
#pragma unroll
    for (int t4 = 0; t4 < 8; ++t4)
      cm = fmaxf(cm, fmaxf(fmaxf(sc4[t4].x, sc4[t4].y), fmaxf(sc4[t4].z, sc4[t4].w)));
    const float nm = fmaxf(m, cm);
    const float scale = __expf(m - nm);
    ssum *= scale; a0 *= scale; a1 *= scale; a2 *= scale; a3 *= scale;
#pragma unroll
    for (int t4 = 0; t4 < 8; ++t4) {
      const int t = ch*32 + t4*4;
      const float e0 = __expf(sc4[t4].x - nm);
      const float e1 = __expf(sc4[t4].y - nm);
      const float e2 = __expf(sc4[t4].z - nm);
      const float e3 = __expf(sc4[t4].w - nm);
      ssum += e0 + e1 + e2 + e3;
      const float4 v0 = vb4[t+0], v1 = vb4[t+1], v2 = vb4[t+2], v3 = vb4[t+3];
      a0 = fmaf(e0, v0.x, a0); a1 = fmaf(e0, v0.y, a1);
      a2 = fmaf(e0, v0.z, a2); a3 = fmaf(e0, v0.w, a3);
      a0 = fmaf(e1, v1.x, a0); a1 = fmaf(e1, v1.y, a1);
      a2 = fmaf(e1, v1.z, a2); a3 = fmaf(e1, v1.w, a3);
      a0 = fmaf(e2, v2.x, a0); a1 = fmaf(e2, v2.y, a1);
      a2 = fmaf(e2, v2.z, a2); a3 = fmaf(e2, v2.w, a3);
      a0 = fmaf(e3, v3.x, a0); a1 = fmaf(e3, v3.y, a1);
      a2 = fmaf(e3, v3.z, a2); a3 = fmaf(e3, v3.w, a3);
    }
    m = nm;
  }
  const float invSsum = 1.f / ssum;

  float4 bias;
  bias.x = a0*invSsum + cbv[0];
  bias.y = a1*invSsum + cbv[1];
  bias.z = a2*invSsum + cbv[2];
  bias.w = a3*invSsum + cbv[3];
#pragma unroll
  for (int gg = 0; gg < kG; ++gg) {
    const float gv = g[gg];
    bias.x = fmaf(gv, wb1[gg*kH + 0], bias.x);
    bias.y = fmaf(gv, wb1[gg*kH + 1], bias.y);
    bias.z = fmaf(gv, wb1[gg*kH + 2], bias.z);
    bias.w = fmaf(gv, wb1[gg*kH + 3], bias.w);
  }

  *(float4*)(ws + WS_BIAS + (size_t)((b*kN + i)*kN + j)*kH) = bias;
}

// ---------------------------------------------------------------------------
// Kernel 3b: attention kernel, TI=4 query rows per block.
//   Coalesced KT logits (float4 q) -> block softmax -> alpha.v -> @Wo + bo.
// ---------------------------------------------------------------------------
static __global__ __launch_bounds__(256, 4)
void attn_kernel(const float* __restrict__ Wo, const float* __restrict__ bo,
                 const float* __restrict__ ws, float* __restrict__ out)
{
  const int i0 = blockIdx.x * TI;
  const int b  = blockIdx.y;
  const int tid = threadIdx.x;
  const int j = tid;

  __shared__ float4 s_w4[TI][kN];        // 16 KB  softmax weights
  __shared__ float  s_red[4][TI][kH];    // 256 B  cross-wave reduce
  __shared__ float  s_part[8][TI][kC];   // 16 KB  alpha.v partials (reused for Wo)
  __shared__ float  s_ao[TI][kC];        // 2 KB

  // ---- logits: acc[i][h] = q_i . k_j  via transposed K (coalesced) ----
  const float* __restrict__ kt = ws + WS_KT + (size_t)b*kC*kN;
  const float4* __restrict__ q4 = (const float4*)(ws + WS_Q + (size_t)(b*kN + i0)*kC);

  float acc[TI][kH];
#pragma unroll
  for (int i = 0; i < TI; ++i)
#pragma unroll
    for (int h = 0; h < kH; ++h) acc[i][h] = 0.f;

#pragma unroll
  for (int h = 0; h < kH; ++h) {
#pragma unroll
    for (int d4 = 0; d4 < kD/4; ++d4) {
      const int d = h*kD + d4*4;
      const float kv0 = kt[(d+0)*kN + j];
      const float kv1 = kt[(d+1)*kN + j];
      const float kv2 = kt[(d+2)*kN + j];
      const float kv3 = kt[(d+3)*kN + j];
#pragma unroll
      for (int i = 0; i < TI; ++i) {
        const float4 qv = q4[i*(kC/4) + h*(kD/4) + d4];
        acc[i][h] = fmaf(qv.x, kv0, acc[i][h]);
        acc[i][h] = fmaf(qv.y, kv1, acc[i][h]);
        acc[i][h] = fmaf(qv.z, kv2, acc[i][h]);
        acc[i][h] = fmaf(qv.w, kv3, acc[i][h]);
      }
    }
  }

  float lg[TI][kH];
#pragma unroll
  for (int i = 0; i < TI; ++i) {
    const float4 bv = *(const float4*)(ws + WS_BIAS + (size_t)((b*kN + i0 + i)*kN + j)*kH);
    lg[i][0] = acc[i][0] + bv.x;
    lg[i][1] = acc[i][1] + bv.y;
    lg[i][2] = acc[i][2] + bv.z;
    lg[i][3] = acc[i][3] + bv.w;
  }

  // ---- softmax over j across the block ----
  const int wave = tid >> 6, lane = tid & 63;
  float mh[TI][kH];
#pragma unroll
  for (int i = 0; i < TI; ++i)
#pragma unroll
    for (int h = 0; h < kH; ++h) {
      float v = lg[i][h];
#pragma unroll
      for (int off = 32; off >= 1; off >>= 1) v = fmaxf(v, __shfl_xor(v, off, 64));
      if (lane == 0) s_red[wave][i][h] = v;
    }
  __syncthreads();
#pragma unroll
  for (int i = 0; i < TI; ++i)
#pragma unroll
    for (int h = 0; h < kH; ++h)
      mh[i][h] = fmaxf(fmaxf(s_red[0][i][h], s_red[1][i][h]),
                       fmaxf(s_red[2][i][h], s_red[3][i][h]));
  __syncthreads();

  float eh[TI][kH];
#pragma unroll
  for (int i = 0; i < TI; ++i)
#pragma unroll
    for (int h = 0; h < kH; ++h) {
      eh[i][h] = __expf(lg[i][h] - mh[i][h]);
      float v = eh[i][h];
#pragma unroll
      for (int off = 32; off >= 1; off >>= 1) v += __shfl_xor(v, off, 64);
      if (lane == 0) s_red[wave][i][h] = v;
    }
  __syncthreads();
#pragma unroll
  for (int i = 0; i < TI; ++i) {
    float4 w;
    float S0 = s_red[0][i][0] + s_red[1][i][0] + s_red[2][i][0] + s_red[3][i][0];
    float S1 = s_red[0][i][1] + s_red[1][i][1] + s_red[2][i][1] + s_red[3][i][1];
    float S2 = s_red[0][i][2] + s_red[1][i][2] + s_red[2][i][2] + s_red[3][i][2];
    float S3 = s_red[0][i][3] + s_red[1][i][3] + s_red[2][i][3] + s_red[3][i][3];
    w.x = eh[i][0] / S0; w.y = eh[i][1] / S1;
    w.z = eh[i][2] / S2; w.w = eh[i][3] / S3;
    s_w4[i][j] = w;
  }
  __syncthreads();

  // ---- ao[i][c] = sum_j w[i][j][c/32] * v[b][j][c] ----
  {
    const int c4  = tid & 31;      // float4 column (c = 4*c4)
    const int grp = tid >> 5;      // 8 groups of 32 j's
    const int hh  = c4 >> 3;       // head for these 4 columns
    const float4* __restrict__ v4 = (const float4*)(ws + WS_V + (size_t)(b*kN)*kC);
    float4 a4[TI];
#pragma unroll
    for (int i = 0; i < TI; ++i) a4[i] = make_float4(0.f, 0.f, 0.f, 0.f);
#pragma unroll 4
    for (int jj = 0; jj < 32; ++jj) {
      const int jr = grp*32 + jj;
      const float4 vv = v4[jr*(kC/4) + c4];
#pragma unroll
      for (int i = 0; i < TI; ++i) {
        const float w = ((const float*)&s_w4[i][jr])[hh];
        a4[i].x = fmaf(w, vv.x, a4[i].x);
        a4[i].y = fmaf(w, vv.y, a4[i].y);
        a4[i].z = fmaf(w, vv.z, a4[i].z);
        a4[i].w = fmaf(w, vv.w, a4[i].w);
      }
    }
#pragma unroll
    for (int i = 0; i < TI; ++i) *(float4*)&s_part[grp][i][c4*4] = a4[i];
  }
  __syncthreads();
#pragma unroll
  for (int rep = 0; rep < 2; ++rep) {
    const int item = rep*256 + tid;
    const int ii = item >> 7, c = item & (kC-1);
    float v = 0.f;
#pragma unroll
    for (int gp = 0; gp < 8; ++gp) v += s_part[gp][ii][c];
    s_ao[ii][c] = v;
  }
  __syncthreads();

  // ---- fused output projection: out = ao @ Wo + bo ----
  {
    const int col = tid & (kC - 1);
    const int seg = tid >> 7;                 // 2 segments of 64 d each
    float accO[TI];
#pragma unroll
    for (int i = 0; i < TI; ++i) accO[i] = (seg == 0) ? bo[col] : 0.f;
    const int d0 = seg * (kC/2);
#pragma unroll 4
    for (int d = d0; d < d0 + kC/2; ++d) {
      const float w = Wo[d*kC + col];
#pragma unroll
      for (int i = 0; i < TI; ++i) accO[i] = fmaf(s_ao[i][d], w, accO[i]);
    }
#pragma unroll
    for (int i = 0; i < TI; ++i) s_part[seg][i][col] = accO[i];
  }
  __syncthreads();
#pragma unroll
  for (int rep = 0; rep < 2; ++rep) {
    const int item = rep*256 + tid;
    const int ii = item >> 7, c = item & (kC-1);
    out[(size_t)(b*kN + i0 + ii)*kC + c] = s_part[0][ii][c] + s_part[1][ii][c];
  }
}

// ---------------------------------------------------------------------------
extern "C" void kernel_launch(void* const* d_in, const int* in_sizes, int n_in,
                              void* d_out, int out_size, void* d_ws, size_t ws_size,
                              hipStream_t stream)
{
  (void)in_sizes; (void)n_in; (void)out_size; (void)ws_size;
  const float* feat    = (const float*)d_in[0];
  const float* centers = (const float*)d_in[1];
  const float* corners = (const float*)d_in[2];
  const float* lang    = (const float*)d_in[3];
  const float* Wq   = (const float*)d_in[4];
  const float* bq   = (const float*)d_in[5];
  const float* Wk   = (const float*)d_in[6];
  const float* bk   = (const float*)d_in[7];
  const float* Wv   = (const float*)d_in[8];
  const float* bv   = (const float*)d_in[9];
  const float* Wo   = (const float*)d_in[10];
  const float* bo   = (const float*)d_in[11];
  const float* Wrel = (const float*)d_in[12];
  const float* brel = (const float*)d_in[13];
  const float* Wtk  = (const float*)d_in[14];
  const float* btk  = (const float*)d_in[15];
  const float* Wtv  = (const float*)d_in[16];
  const float* btv  = (const float*)d_in[17];
  const float* Wbias = (const float*)d_in[18];
  const float* bbias = (const float*)d_in[19];

  float* ws  = (float*)d_ws;   // ~12.1 MB
  float* out = (float*)d_out;

  proj_kernel<<<dim3(kProjQKV + kProjTxt + kProjSize), dim3(256), 0, stream>>>(
      feat, lang, corners, Wq, bq, Wk, bk, Wv, bv, Wtk, btk, Wtv, btv, ws);
  fold_kernel<<<dim3(kFoldBlocks), dim3(256), 0, stream>>>(
      Wrel, brel, Wbias, bbias, ws);
  bias_kernel<<<dim3(kN, kB), dim3(256), 0, stream>>>(centers, ws, ws);
  attn_kernel<<<dim3(kN/TI, kB), dim3(256), 0, stream>>>(Wo, bo, ws, out);
}

// Round 7
// 163.649 us; speedup vs baseline: 1.0886x; 1.0886x over previous
//
#include <hip/hip_runtime.h>
#include <math.h>

// Problem constants (B, N, C, T, H, G) = (8, 256, 128, 64, 4, 12), D = 32
namespace {
constexpr int kB = 8, kN = 256, kC = 128, kT = 64, kH = 4, kG = 12, kD = 32;
constexpr float kEps = 1e-6f;
constexpr float kInvSqrtC = 0.08838834764831845f;   // 1/sqrt(128)
constexpr float kInvSqrtD = 0.17677669529663687f;   // 1/sqrt(32)

// workspace layout (float offsets)
constexpr int WS_Q     = 0;                          // [b][n][c]  (pre-scaled by 1/sqrt(D))
constexpr int WS_KT    = WS_Q + kB*kN*kC;            // [b][c][n]  TRANSPOSED K
constexpr int WS_V     = WS_KT + kB*kN*kC;           // [b][n][c]
constexpr int WS_SIZES = WS_V + kB*kN*kC;            // [b][n][3]
constexpr int WS_KTXT  = WS_SIZES + kB*kN*3;         // [b][t][c]
constexpr int WS_VTXT  = WS_KTXT + kB*kT*kC;         // [b][t][c]
constexpr int WS_WKF   = WS_VTXT + kB*kT*kC;         // [b][g][t] = (Wrel @ k_txt^T)/sqrt(C)
constexpr int WS_SK    = WS_WKF + kB*kG*kT;          // [b][t]    = (brel . k_txt[t])/sqrt(C)
constexpr int WS_VB    = WS_SK + kB*kT;              // [b][t][h] = v_txt @ Wbias
constexpr int WS_WB1   = WS_VB + kB*kT*kH;           // [g][h]    = Wrel @ Wbias
constexpr int WS_CB    = WS_WB1 + kG*kH;             // [h]       = brel@Wbias + bbias
constexpr int WS_BIAS  = WS_CB + kH;                 // [b][i][j][h]  (8 MB)

// proj grid: 4 rows per block, 256 threads (each thread: 2 rows x 1 col)
constexpr int kProjQKV  = (kB*kN)/4;     // 512 blocks
constexpr int kProjTxt  = (kB*kT)/4;     // 128 blocks
constexpr int kProjSize = (kB*kN)/256;   // 8 blocks (sizes from corners)

// fold tasks: per batch 768 (WkF) + 64 (sk) + 256 (VB) = 1088; global 48+4
constexpr int kTasksPerB = kG*kT + kT + kT*kH;       // 1088
constexpr int kTasksAll  = kB*kTasksPerB;            // 8704
constexpr int kTasksTot  = kTasksAll + kG*kH + kH;   // 8756
constexpr int kFoldBlocks = (kTasksTot + 3) / 4;     // 4 waves / block

constexpr int TI = 2;   // i-rows per attn block: grid 1024 = 4 blocks/CU
}

// ---------------------------------------------------------------------------
// Kernel 1: fused linear projections.
//   blocks [0,512)    : q/k/v, 4 feat rows per block (thread = 2 rows x 1 col)
//   blocks [512,640)  : k_txt/v_txt, 4 lang rows per block
//   blocks [640,648)  : box sizes from corners (256 boxes per block)
// ---------------------------------------------------------------------------
static __global__ __launch_bounds__(256)
void proj_kernel(const float* __restrict__ feat, const float* __restrict__ lang,
                 const float* __restrict__ corners,
                 const float* __restrict__ Wq, const float* __restrict__ bq,
                 const float* __restrict__ Wk, const float* __restrict__ bk,
                 const float* __restrict__ Wv, const float* __restrict__ bv,
                 const float* __restrict__ Wtk, const float* __restrict__ btk,
                 const float* __restrict__ Wtv, const float* __restrict__ btv,
                 float* __restrict__ ws)
{
  const int blk = blockIdx.x;
  const int tid = threadIdx.x;
  __shared__ float rows[4][kC];

  if (blk < kProjQKV) {
    const int r0 = blk * 4;                       // global row (b*N + n)
    rows[tid >> 7][tid & 127] = feat[(size_t)r0*kC + tid];
    rows[(tid + 256) >> 7][tid & 127] = feat[(size_t)r0*kC + tid + 256];
    __syncthreads();

    const int c = tid & 127;
    const int p = tid >> 7;                       // row-pair select
    const int ra = p*2, rb = p*2 + 1;

    float aq0 = bq[c], aq1 = aq0;
    float ak0 = bk[c], ak1 = ak0;
    float av0 = bv[c], av1 = av0;
#pragma unroll 4
    for (int d = 0; d < kC; ++d) {
      const float wq = Wq[d*kC + c], wk = Wk[d*kC + c], wv = Wv[d*kC + c];
      const float fa = rows[ra][d], fb = rows[rb][d];
      aq0 = fmaf(fa, wq, aq0); aq1 = fmaf(fb, wq, aq1);
      ak0 = fmaf(fa, wk, ak0); ak1 = fmaf(fb, wk, ak1);
      av0 = fmaf(fa, wv, av0); av1 = fmaf(fb, wv, av1);
    }

    const int gra = r0 + ra, grb = r0 + rb;
    const int bb = r0 / kN, n0 = r0 % kN;
    ws[WS_Q + (size_t)gra*kC + c] = aq0 * kInvSqrtD;   // fold 1/sqrt(D)
    ws[WS_Q + (size_t)grb*kC + c] = aq1 * kInvSqrtD;
    ws[WS_KT + (size_t)bb*kC*kN + c*kN + n0 + ra] = ak0;   // transposed K
    ws[WS_KT + (size_t)bb*kC*kN + c*kN + n0 + rb] = ak1;
    ws[WS_V + (size_t)gra*kC + c] = av0;
    ws[WS_V + (size_t)grb*kC + c] = av1;
  } else if (blk < kProjQKV + kProjTxt) {
    const int r0 = (blk - kProjQKV) * 4;          // 0 .. B*T-1
    rows[tid >> 7][tid & 127] = lang[(size_t)r0*kC + tid];
    rows[(tid + 256) >> 7][tid & 127] = lang[(size_t)r0*kC + tid + 256];
    __syncthreads();

    const int c = tid & 127;
    const int p = tid >> 7;
    const int ra = p*2, rb = p*2 + 1;

    float ak0 = btk[c], ak1 = ak0;
    float av0 = btv[c], av1 = av0;
#pragma unroll 4
    for (int d = 0; d < kC; ++d) {
      const float wk = Wtk[d*kC + c], wv = Wtv[d*kC + c];
      const float fa = rows[ra][d], fb = rows[rb][d];
      ak0 = fmaf(fa, wk, ak0); ak1 = fmaf(fb, wk, ak1);
      av0 = fmaf(fa, wv, av0); av1 = fmaf(fb, wv, av1);
    }
    ws[WS_KTXT + (size_t)(r0 + ra)*kC + c] = ak0;
    ws[WS_KTXT + (size_t)(r0 + rb)*kC + c] = ak1;
    ws[WS_VTXT + (size_t)(r0 + ra)*kC + c] = av0;
    ws[WS_VTXT + (size_t)(r0 + rb)*kC + c] = av1;
  } else {
    const int n = (blk - kProjQKV - kProjTxt) * 256 + tid;  // 0 .. B*N-1
    const float* cp = corners + (size_t)n * 24;
    float mn0 = cp[0], mn1 = cp[1], mn2 = cp[2];
    float mx0 = mn0, mx1 = mn1, mx2 = mn2;
#pragma unroll
    for (int k = 1; k < 8; ++k) {
      const float v0 = cp[k*3+0], v1 = cp[k*3+1], v2 = cp[k*3+2];
      mn0 = fminf(mn0, v0); mx0 = fmaxf(mx0, v0);
      mn1 = fminf(mn1, v1); mx1 = fmaxf(mx1, v1);
      mn2 = fminf(mn2, v2); mx2 = fmaxf(mx2, v2);
    }
    ws[WS_SIZES + n*3 + 0] = mx0 - mn0;
    ws[WS_SIZES + n*3 + 1] = mx1 - mn1;
    ws[WS_SIZES + n*3 + 2] = mx2 - mn2;
  }
}

// ---------------------------------------------------------------------------
// Kernel 2: algebraic folds — one WAVE per 128-length dot product.
// WkF and sk outputs are pre-scaled by 1/sqrt(C).
// ---------------------------------------------------------------------------
static __global__ __launch_bounds__(256)
void fold_kernel(const float* __restrict__ Wrel, const float* __restrict__ brel,
                 const float* __restrict__ Wbias, const float* __restrict__ bbias,
                 float* __restrict__ ws)
{
  const int task = blockIdx.x * 4 + (threadIdx.x >> 6);
  const int lane = threadIdx.x & 63;
  if (task >= kTasksTot) return;

  const float* x; const float* y; float* outp; float addend = 0.f;
  float mul = 1.f;
  int ystride4 = 0;   // if nonzero, y is a column of Wbias (stride kH)

  if (task < kTasksAll) {
    const int b = task / kTasksPerB;
    const int tt = task % kTasksPerB;
    const float* ktxt = ws + WS_KTXT + (size_t)b*kT*kC;
    const float* vtxt = ws + WS_VTXT + (size_t)b*kT*kC;
    if (tt < kG*kT) {
      const int g = tt >> 6, t = tt & 63;
      x = Wrel + g*kC; y = ktxt + t*kC; mul = kInvSqrtC;
      outp = ws + WS_WKF + b*kG*kT + g*kT + t;
    } else if (tt < kG*kT + kT) {
      const int t = tt - kG*kT;
      x = brel; y = ktxt + t*kC; mul = kInvSqrtC;
      outp = ws + WS_SK + b*kT + t;
    } else {
      const int idx = tt - kG*kT - kT;
      const int t = idx >> 2, h = idx & 3;
      x = vtxt + t*kC; y = Wbias + h; ystride4 = 1;
      outp = ws + WS_VB + b*kT*kH + t*kH + h;
    }
  } else {
    const int tt = task - kTasksAll;
    if (tt < kG*kH) {
      const int g = tt >> 2, h = tt & 3;
      x = Wrel + g*kC; y = Wbias + h; ystride4 = 1;
      outp = ws + WS_WB1 + g*kH + h;
    } else {
      const int h = tt - kG*kH;
      x = brel; y = Wbias + h; ystride4 = 1;
      addend = bbias[h];
      outp = ws + WS_CB + h;
    }
  }

  float p;
  if (ystride4) {
    p = x[lane]*y[lane*kH] + x[lane+64]*y[(lane+64)*kH];
  } else {
    p = x[lane]*y[lane] + x[lane+64]*y[lane+64];
  }
#pragma unroll
  for (int off = 32; off >= 1; off >>= 1) p += __shfl_xor(p, off, 64);
  if (lane == 0) *outp = p * mul + addend;
}

// ---------------------------------------------------------------------------
// Kernel 3a: bias kernel. One block per (b, i); thread j in [0,256).
//   geom -> folded scores (float4-vectorized uniform loads, online softmax)
//   -> bias[4] -> ws.
// ---------------------------------------------------------------------------
static __global__ __launch_bounds__(256, 4)
void bias_kernel(const float* __restrict__ centers,
                 const float* __restrict__ ws_ro, float* __restrict__ ws)
{
  const int i = blockIdx.x;
  const int b = blockIdx.y;
  const int j = threadIdx.x;

  // uniform (scalar) i-operands
  const float* cI = centers + (size_t)(b*kN + i)*3;
  const float* sI = ws_ro + WS_SIZES + (size_t)(b*kN + i)*3;
  const float cix = cI[0], ciy = cI[1], ciz = cI[2];
  const float six = sI[0], siy = sI[1], siz = sI[2];

  // per-thread j-operands
  const float* cJ = centers + (size_t)(b*kN + j)*3;
  const float* sJ = ws_ro + WS_SIZES + (size_t)(b*kN + j)*3;

  float g[kG];
  {
    const float dx = cJ[0] - cix;
    const float dy = cJ[1] - ciy;
    const float dz = cJ[2] - ciz;
    const float dist = sqrtf(dx*dx + dy*dy + dz*dz);
    const float horiz = sqrtf(dx*dx + dy*dy);
    g[0] = dx; g[1] = dy; g[2] = dz;
    g[3] = __logf(dist + kEps);
    g[4] = horiz;
    g[5] = dz / (dist + kEps);
    const float sjx = sJ[0], sjy = sJ[1], sjz = sJ[2];
    g[6] = sjx - six; g[7] = sjy - siy; g[8] = sjz - siz;
    g[9]  = sjx / (six + kEps);
    g[10] = sjy / (siy + kEps);
    g[11] = sjz / (siz + kEps);
  }

  // float4 views of the uniform per-batch tables (all 16B-aligned)
  const float4* __restrict__ wkf4 = (const float4*)(ws_ro + WS_WKF + b*kG*kT); // [g][t/4]
  const float4* __restrict__ sk4  = (const float4*)(ws_ro + WS_SK  + b*kT);    // [t/4]
  const float4* __restrict__ vb4  = (const float4*)(ws_ro + WS_VB  + b*kT*kH); // [t] (h in lanes)
  const float* __restrict__ wb1 = ws_ro + WS_WB1;
  const float* __restrict__ cbv = ws_ro + WS_CB;

  float m = -1e30f, ssum = 0.f;
  float a0 = 0.f, a1 = 0.f, a2 = 0.f, a3 = 0.f;
#pragma unroll
  for (int ch = 0; ch < 2; ++ch) {            // two chunks of 32 t's
    float4 sc4[8];
#pragma unroll
    for (int t4 = 0; t4 < 8; ++t4) sc4[t4] = sk4[ch*8 + t4];
#pragma unroll
    for (int gg = 0; gg < kG; ++gg) {
      const float gv = g[gg];
#pragma unroll
      for (int t4 = 0; t4 < 8; ++t4) {
        const float4 wv = wkf4[gg*(kT/4) + ch*8 + t4];
        sc4[t4].x = fmaf(gv, wv.x, sc4[t4].x);
        sc4[t4].y = fmaf(gv, wv.y, sc4[t4].y);
        sc4[t4].z = fmaf(gv, wv.z, sc4[t4].z);
        sc4[t4].w = fmaf(gv, wv.w, sc4[t4].w);
      }
    }
    float cm = -1e30f;
#pragma unroll
    for (int t4 = 0; t4 < 8; ++t4)
      cm = fmaxf(cm, fmaxf(fmaxf(sc4[t4].x, sc4[t4].y), fmaxf(sc4[t4].z, sc4[t4].w)));
    const float nm = fmaxf(m, cm);
    const float scale = __expf(m - nm);
    ssum *= scale; a0 *= scale; a1 *= scale; a2 *= scale; a3 *= scale;
#pragma unroll
    for (int t4 = 0; t4 < 8; ++t4) {
      const int t = ch*32 + t4*4;
      const float e0 = __expf(sc4[t4].x - nm);
      const float e1 = __expf(sc4[t4].y - nm);
      const float e2 = __expf(sc4[t4].z - nm);
      const float e3 = __expf(sc4[t4].w - nm);
      ssum += e0 + e1 + e2 + e3;
      const float4 v0 = vb4[t+0], v1 = vb4[t+1], v2 = vb4[t+2], v3 = vb4[t+3];
      a0 = fmaf(e0, v0.x, a0); a1 = fmaf(e0, v0.y, a1);
      a2 = fmaf(e0, v0.z, a2); a3 = fmaf(e0, v0.w, a3);
      a0 = fmaf(e1, v1.x, a0); a1 = fmaf(e1, v1.y, a1);
      a2 = fmaf(e1, v1.z, a2); a3 = fmaf(e1, v1.w, a3);
      a0 = fmaf(e2, v2.x, a0); a1 = fmaf(e2, v2.y, a1);
      a2 = fmaf(e2, v2.z, a2); a3 = fmaf(e2, v2.w, a3);
      a0 = fmaf(e3, v3.x, a0); a1 = fmaf(e3, v3.y, a1);
      a2 = fmaf(e3, v3.z, a2); a3 = fmaf(e3, v3.w, a3);
    }
    m = nm;
  }
  const float invSsum = 1.f / ssum;

  float4 bias;
  bias.x = a0*invSsum + cbv[0];
  bias.y = a1*invSsum + cbv[1];
  bias.z = a2*invSsum + cbv[2];
  bias.w = a3*invSsum + cbv[3];
#pragma unroll
  for (int gg = 0; gg < kG; ++gg) {
    const float gv = g[gg];
    bias.x = fmaf(gv, wb1[gg*kH + 0], bias.x);
    bias.y = fmaf(gv, wb1[gg*kH + 1], bias.y);
    bias.z = fmaf(gv, wb1[gg*kH + 2], bias.z);
    bias.w = fmaf(gv, wb1[gg*kH + 3], bias.w);
  }

  *(float4*)(ws + WS_BIAS + (size_t)((b*kN + i)*kN + j)*kH) = bias;
}

// ---------------------------------------------------------------------------
// Kernel 3b: attention kernel, TI=2 query rows per block (grid 1024).
//   Coalesced KT logits (scalar uniform q -> s_load) -> block softmax
//   -> alpha.v -> @Wo + bo.
// ---------------------------------------------------------------------------
static __global__ __launch_bounds__(256, 4)
void attn_kernel(const float* __restrict__ Wo, const float* __restrict__ bo,
                 const float* __restrict__ ws, float* __restrict__ out)
{
  const int i0 = blockIdx.x * TI;
  const int b  = blockIdx.y;
  const int tid = threadIdx.x;
  const int j = tid;

  __shared__ float4 s_w4[TI][kN];        // 8 KB  softmax weights
  __shared__ float  s_red[4][TI][kH];    // 128 B cross-wave reduce
  __shared__ float  s_part[8][TI][kC];   // 8 KB  alpha.v partials (reused for Wo)
  __shared__ float  s_ao[TI][kC];        // 1 KB

  // ---- logits: acc[i][h] = q_i . k_j via transposed K (coalesced kt,
  //      block-uniform scalar q -> compiler scalarizes to s_load) ----
  const float* __restrict__ kt = ws + WS_KT + (size_t)b*kC*kN;
  const float* __restrict__ qb = ws + WS_Q + (size_t)(b*kN + i0)*kC;  // uniform

  float acc[TI][kH];
#pragma unroll
  for (int i = 0; i < TI; ++i)
#pragma unroll
    for (int h = 0; h < kH; ++h) acc[i][h] = 0.f;

#pragma unroll
  for (int h = 0; h < kH; ++h) {
#pragma unroll 4
    for (int dd = 0; dd < kD; ++dd) {
      const int d = h*kD + dd;
      const float kv = kt[d*kN + j];
#pragma unroll
      for (int i = 0; i < TI; ++i)
        acc[i][h] = fmaf(qb[i*kC + d], kv, acc[i][h]);
    }
  }

  float lg[TI][kH];
#pragma unroll
  for (int i = 0; i < TI; ++i) {
    const float4 bv = *(const float4*)(ws + WS_BIAS + (size_t)((b*kN + i0 + i)*kN + j)*kH);
    lg[i][0] = acc[i][0] + bv.x;
    lg[i][1] = acc[i][1] + bv.y;
    lg[i][2] = acc[i][2] + bv.z;
    lg[i][3] = acc[i][3] + bv.w;
  }

  // ---- softmax over j across the block ----
  const int wave = tid >> 6, lane = tid & 63;
  float mh[TI][kH];
#pragma unroll
  for (int i = 0; i < TI; ++i)
#pragma unroll
    for (int h = 0; h < kH; ++h) {
      float v = lg[i][h];
#pragma unroll
      for (int off = 32; off >= 1; off >>= 1) v = fmaxf(v, __shfl_xor(v, off, 64));
      if (lane == 0) s_red[wave][i][h] = v;
    }
  __syncthreads();
#pragma unroll
  for (int i = 0; i < TI; ++i)
#pragma unroll
    for (int h = 0; h < kH; ++h)
      mh[i][h] = fmaxf(fmaxf(s_red[0][i][h], s_red[1][i][h]),
                       fmaxf(s_red[2][i][h], s_red[3][i][h]));
  __syncthreads();

  float eh[TI][kH];
#pragma unroll
  for (int i = 0; i < TI; ++i)
#pragma unroll
    for (int h = 0; h < kH; ++h) {
      eh[i][h] = __expf(lg[i][h] - mh[i][h]);
      float v = eh[i][h];
#pragma unroll
      for (int off = 32; off >= 1; off >>= 1) v += __shfl_xor(v, off, 64);
      if (lane == 0) s_red[wave][i][h] = v;
    }
  __syncthreads();
#pragma unroll
  for (int i = 0; i < TI; ++i) {
    float4 w;
    float S0 = s_red[0][i][0] + s_red[1][i][0] + s_red[2][i][0] + s_red[3][i][0];
    float S1 = s_red[0][i][1] + s_red[1][i][1] + s_red[2][i][1] + s_red[3][i][1];
    float S2 = s_red[0][i][2] + s_red[1][i][2] + s_red[2][i][2] + s_red[3][i][2];
    float S3 = s_red[0][i][3] + s_red[1][i][3] + s_red[2][i][3] + s_red[3][i][3];
    w.x = eh[i][0] / S0; w.y = eh[i][1] / S1;
    w.z = eh[i][2] / S2; w.w = eh[i][3] / S3;
    s_w4[i][j] = w;
  }
  __syncthreads();

  // ---- ao[i][c] = sum_j w[i][j][c/32] * v[b][j][c] ----
  {
    const int c4  = tid & 31;      // float4 column (c = 4*c4)
    const int grp = tid >> 5;      // 8 groups of 32 j's
    const int hh  = c4 >> 3;       // head for these 4 columns
    const float4* __restrict__ v4 = (const float4*)(ws + WS_V + (size_t)(b*kN)*kC);
    float4 a4[TI];
#pragma unroll
    for (int i = 0; i < TI; ++i) a4[i] = make_float4(0.f, 0.f, 0.f, 0.f);
#pragma unroll 4
    for (int jj = 0; jj < 32; ++jj) {
      const int jr = grp*32 + jj;
      const float4 vv = v4[jr*(kC/4) + c4];
#pragma unroll
      for (int i = 0; i < TI; ++i) {
        const float w = ((const float*)&s_w4[i][jr])[hh];
        a4[i].x = fmaf(w, vv.x, a4[i].x);
        a4[i].y = fmaf(w, vv.y, a4[i].y);
        a4[i].z = fmaf(w, vv.z, a4[i].z);
        a4[i].w = fmaf(w, vv.w, a4[i].w);
      }
    }
#pragma unroll
    for (int i = 0; i < TI; ++i) *(float4*)&s_part[grp][i][c4*4] = a4[i];
  }
  __syncthreads();
  {
    // TI*kC = 256 items == 256 threads: one partial-sum each
    const int ii = tid >> 7, c = tid & (kC-1);
    float v = 0.f;
#pragma unroll
    for (int gp = 0; gp < 8; ++gp) v += s_part[gp][ii][c];
    s_ao[ii][c] = v;
  }
  __syncthreads();

  // ---- fused output projection: out = ao @ Wo + bo ----
  {
    const int col = tid & (kC - 1);
    const int seg = tid >> 7;                 // 2 segments of 64 d each
    float accO[TI];
#pragma unroll
    for (int i = 0; i < TI; ++i) accO[i] = (seg == 0) ? bo[col] : 0.f;
    const int d0 = seg * (kC/2);
#pragma unroll 4
    for (int d = d0; d < d0 + kC/2; ++d) {
      const float w = Wo[d*kC + col];
#pragma unroll
      for (int i = 0; i < TI; ++i) accO[i] = fmaf(s_ao[i][d], w, accO[i]);
    }
#pragma unroll
    for (int i = 0; i < TI; ++i) s_part[seg][i][col] = accO[i];
  }
  __syncthreads();
  {
    const int ii = tid >> 7, c = tid & (kC-1);
    out[(size_t)(b*kN + i0 + ii)*kC + c] = s_part[0][ii][c] + s_part[1][ii][c];
  }
}

// ---------------------------------------------------------------------------
extern "C" void kernel_launch(void* const* d_in, const int* in_sizes, int n_in,
                              void* d_out, int out_size, void* d_ws, size_t ws_size,
                              hipStream_t stream)
{
  (void)in_sizes; (void)n_in; (void)out_size; (void)ws_size;
  const float* feat    = (const float*)d_in[0];
  const float* centers = (const float*)d_in[1];
  const float* corners = (const float*)d_in[2];
  const float* lang    = (const float*)d_in[3];
  const float* Wq   = (const float*)d_in[4];
  const float* bq   = (const float*)d_in[5];
  const float* Wk   = (const float*)d_in[6];
  const float* bk   = (const float*)d_in[7];
  const float* Wv   = (const float*)d_in[8];
  const float* bv   = (const float*)d_in[9];
  const float* Wo   = (const float*)d_in[10];
  const float* bo   = (const float*)d_in[11];
  const float* Wrel = (const float*)d_in[12];
  const float* brel = (const float*)d_in[13];
  const float* Wtk  = (const float*)d_in[14];
  const float* btk  = (const float*)d_in[15];
  const float* Wtv  = (const float*)d_in[16];
  const float* btv  = (const float*)d_in[17];
  const float* Wbias = (const float*)d_in[18];
  const float* bbias = (const float*)d_in[19];

  float* ws  = (float*)d_ws;   // ~12.1 MB
  float* out = (float*)d_out;

  proj_kernel<<<dim3(kProjQKV + kProjTxt + kProjSize), dim3(256), 0, stream>>>(
      feat, lang, corners, Wq, bq, Wk, bk, Wv, bv, Wtk, btk, Wtv, btv, ws);
  fold_kernel<<<dim3(kFoldBlocks), dim3(256), 0, stream>>>(
      Wrel, brel, Wbias, bbias, ws);
  bias_kernel<<<dim3(kN, kB), dim3(256), 0, stream>>>(centers, ws, ws);
  attn_kernel<<<dim3(kN/TI, kB), dim3(256), 0, stream>>>(Wo, bo, ws, out);
}